// Round 3
// baseline (85.783 us; speedup 1.0000x reference)
//
#include <hip/hip_runtime.h>
#include <hip/hip_bf16.h>
#include <math.h>

// Problem constants: B=4, Q=100, T=20, H=W=128 (HW=16384), C=80
#define B_ 4
#define Q_ 100
#define T_ 20
#define C_ 80
#define HW_ 16384

#define S_ 16                    // segments over HW
#define QG_ 5                    // queries per group/block
#define GROUPS_ (B_ * Q_ / QG_)  // 80
#define SEG4_ (HW_ / S_ / 4)     // 256 float4 per segment
#define TW_ 5                    // t's per wave (4 waves * 5 = T)
#define QREC_ 41                 // per-q record: 20 L + 20 I + 1 osum
#define REC_ (QG_ * QREC_)       // 205 floats per (group,seg)

__device__ __forceinline__ float wave_reduce_sum(float v) {
    v += __shfl_down(v, 32);
    v += __shfl_down(v, 16);
    v += __shfl_down(v, 8);
    v += __shfl_down(v, 4);
    v += __shfl_down(v, 2);
    v += __shfl_down(v, 1);
    return v;
}

// Kernel 1: per-(b,t) sum of target masks -> tsum[b*T+t]
__global__ __launch_bounds__(256) void tgt_sum_kernel(const float* __restrict__ tgt,
                                                      float* __restrict__ tsum) {
    const int bt = blockIdx.x;
    const float4* p = (const float4*)(tgt + (size_t)bt * HW_);
    float s = 0.f;
    for (int i = threadIdx.x; i < HW_ / 4; i += blockDim.x) {
        float4 v = p[i];
        s += (v.x + v.y) + (v.z + v.w);
    }
    s = wave_reduce_sum(s);
    __shared__ float red[4];
    const int lane = threadIdx.x & 63;
    const int wave = threadIdx.x >> 6;
    if (lane == 0) red[wave] = s;
    __syncthreads();
    if (threadIdx.x == 0) tsum[bt] = red[0] + red[1] + red[2] + red[3];
}

// Kernel 2: partial sums per (5-query group, segment).
// 256 threads = 4 waves; wave w handles t in [5w,5w+5) for all 5 queries.
__global__ __launch_bounds__(256, 4) void partial_kernel(const float* __restrict__ outm,
                                                         const float* __restrict__ tgtm,
                                                         float* __restrict__ ws) {
    const int seg = blockIdx.x & (S_ - 1);
    const int grp = blockIdx.x / S_;
    const int b     = grp / (Q_ / QG_);
    const int qbase = (grp % (Q_ / QG_)) * QG_;

    const int lane = threadIdx.x & 63;
    const int wave = threadIdx.x >> 6;
    const int t0   = wave * TW_;

    const float4* o4 = (const float4*)(outm + ((size_t)b * Q_ + qbase) * HW_) + seg * SEG4_;
    const float4* g4 = (const float4*)(tgtm + (size_t)b * T_ * HW_) + seg * SEG4_;

    float accL[QG_][TW_];
    float accI[QG_][TW_];
    float osum[QG_];
#pragma unroll
    for (int qi = 0; qi < QG_; ++qi) {
        osum[qi] = 0.f;
#pragma unroll
        for (int tj = 0; tj < TW_; ++tj) { accL[qi][tj] = 0.f; accI[qi][tj] = 0.f; }
    }

    for (int i = lane; i < SEG4_; i += 64) {
        float4 o[QG_];
#pragma unroll
        for (int qi = 0; qi < QG_; ++qi) {
            o[qi] = o4[(size_t)qi * (HW_ / 4) + i];
            osum[qi] += (o[qi].x + o[qi].y) + (o[qi].z + o[qi].w);
        }
#pragma unroll
        for (int tj = 0; tj < TW_; ++tj) {
            const float4 g = g4[(size_t)(t0 + tj) * (HW_ / 4) + i];
#pragma unroll
            for (int qi = 0; qi < QG_; ++qi) {
                accL[qi][tj] += (fabsf(o[qi].x - g.x) + fabsf(o[qi].y - g.y)) +
                                (fabsf(o[qi].z - g.z) + fabsf(o[qi].w - g.w));
                accI[qi][tj] = fmaf(o[qi].x, g.x, accI[qi][tj]);
                accI[qi][tj] = fmaf(o[qi].y, g.y, accI[qi][tj]);
                accI[qi][tj] = fmaf(o[qi].z, g.z, accI[qi][tj]);
                accI[qi][tj] = fmaf(o[qi].w, g.w, accI[qi][tj]);
            }
        }
    }

    float* rec = ws + ((size_t)grp * S_ + seg) * REC_;
#pragma unroll
    for (int qi = 0; qi < QG_; ++qi) {
#pragma unroll
        for (int tj = 0; tj < TW_; ++tj) {
            const float vL = wave_reduce_sum(accL[qi][tj]);
            const float vI = wave_reduce_sum(accI[qi][tj]);
            if (lane == 0) {
                rec[qi * QREC_ + (t0 + tj)]      = vL;
                rec[qi * QREC_ + 20 + (t0 + tj)] = vI;
            }
        }
        const float vo = wave_reduce_sum(osum[qi]);
        if (wave == 0 && lane == 0) rec[qi * QREC_ + 40] = vo;
    }
}

// Kernel 3: reduce segments + epilogue (softmax class cost + dice).
__global__ __launch_bounds__(64) void finalize_kernel(const float* __restrict__ probs,
                                                      const int*   __restrict__ labels,
                                                      const float* __restrict__ tsum,
                                                      const float* __restrict__ ws,
                                                      float* __restrict__ out) {
    const int bq = blockIdx.x;
    const int b = bq / Q_;
    const int q = bq % Q_;
    const int grp = b * (Q_ / QG_) + q / QG_;
    const int qi  = q % QG_;

    __shared__ float s_logit[C_];
    for (int c = threadIdx.x; c < C_; c += 64)
        s_logit[c] = probs[(size_t)bq * C_ + c];
    __syncthreads();

    const int t = threadIdx.x;
    if (t < T_) {
        float L = 0.f, I = 0.f, os = 0.f;
#pragma unroll
        for (int s = 0; s < S_; ++s) {
            const float* rec = ws + ((size_t)grp * S_ + s) * REC_ + qi * QREC_;
            L += rec[t];
            I += rec[20 + t];
            os += rec[40];
        }
        float m = -INFINITY;
#pragma unroll
        for (int c = 0; c < C_; ++c) m = fmaxf(m, s_logit[c]);
        float sum = 0.f;
#pragma unroll
        for (int c = 0; c < C_; ++c) sum += __expf(s_logit[c] - m);
        const int lab = labels[b * T_ + t];
        const float p = __expf(s_logit[lab] - m) / sum;

        const float denom = os + tsum[b * T_ + t];
        const float dice = 1.f - (2.f * I + 1.f) / (denom + 1.f);

        out[(size_t)bq * T_ + t] = L - p + dice;
    }
}

extern "C" void kernel_launch(void* const* d_in, const int* in_sizes, int n_in,
                              void* d_out, int out_size, void* d_ws, size_t ws_size,
                              hipStream_t stream) {
    const float* out_probs     = (const float*)d_in[0]; // [B,Q,C]
    const float* out_masks     = (const float*)d_in[1]; // [B,Q,H,W]
    const float* target_masks  = (const float*)d_in[2]; // [B,T,H,W]
    const int*   target_labels = (const int*)d_in[3];   // [B,T]
    float* out = (float*)d_out;                         // [B,Q,T]

    float* tsum     = (float*)d_ws;                     // B*T floats
    float* partials = tsum + B_ * T_;                   // GROUPS_*S_*REC_ floats (~1.05 MB)

    tgt_sum_kernel<<<B_ * T_, 256, 0, stream>>>(target_masks, tsum);
    partial_kernel<<<GROUPS_ * S_, 256, 0, stream>>>(out_masks, target_masks, partials);
    finalize_kernel<<<B_ * Q_, 64, 0, stream>>>(out_probs, target_labels, tsum, partials, out);
}

// Round 4
// 43.697 us; speedup vs baseline: 1.9632x; 1.9632x over previous
//
#include <hip/hip_runtime.h>
#include <hip/hip_bf16.h>
#include <math.h>

// Problem constants: B=4, Q=100, T=20, H=W=128 (HW=16384), C=80
#define B_ 4
#define Q_ 100
#define T_ 20
#define C_ 80
#define HW_ 16384

#define S_ 8                     // segments over HW
#define QG_ 4                    // queries per group/block (keeps regs < 128, no spill)
#define GROUPS_ (B_ * Q_ / QG_)  // 100
#define SEG4_ (HW_ / S_ / 4)     // 512 float4 per segment
#define TW_ 5                    // t's per wave (4 waves * 5 = T)
#define QREC_ 41                 // per-q record: 20 L + 20 I + 1 osum
#define REC_ (QG_ * QREC_)       // 164 floats per (group,seg)

__device__ __forceinline__ float wave_reduce_sum(float v) {
    v += __shfl_down(v, 32);
    v += __shfl_down(v, 16);
    v += __shfl_down(v, 8);
    v += __shfl_down(v, 4);
    v += __shfl_down(v, 2);
    v += __shfl_down(v, 1);
    return v;
}

// Kernel 1: per-(b,t) sum of target masks -> tsum[b*T+t]
__global__ __launch_bounds__(256) void tgt_sum_kernel(const float* __restrict__ tgt,
                                                      float* __restrict__ tsum) {
    const int bt = blockIdx.x;
    const float4* p = (const float4*)(tgt + (size_t)bt * HW_);
    float s = 0.f;
    for (int i = threadIdx.x; i < HW_ / 4; i += blockDim.x) {
        float4 v = p[i];
        s += (v.x + v.y) + (v.z + v.w);
    }
    s = wave_reduce_sum(s);
    __shared__ float red[4];
    const int lane = threadIdx.x & 63;
    const int wave = threadIdx.x >> 6;
    if (lane == 0) red[wave] = s;
    __syncthreads();
    if (threadIdx.x == 0) tsum[bt] = red[0] + red[1] + red[2] + red[3];
}

// Kernel 2: partial sums per (4-query group, segment).
// 256 threads = 4 waves; wave w handles t in [5w,5w+5) for all 4 queries.
__global__ __launch_bounds__(256) void partial_kernel(const float* __restrict__ outm,
                                                      const float* __restrict__ tgtm,
                                                      float* __restrict__ ws) {
    const int seg = blockIdx.x & (S_ - 1);
    const int grp = blockIdx.x / S_;
    const int b     = grp / (Q_ / QG_);
    const int qbase = (grp % (Q_ / QG_)) * QG_;

    const int lane = threadIdx.x & 63;
    const int wave = threadIdx.x >> 6;
    const int t0   = wave * TW_;

    const float4* o4 = (const float4*)(outm + ((size_t)b * Q_ + qbase) * HW_) + seg * SEG4_;
    const float4* g4 = (const float4*)(tgtm + (size_t)b * T_ * HW_) + seg * SEG4_;

    float accL[QG_][TW_];
    float accI[QG_][TW_];
    float osum[QG_];
#pragma unroll
    for (int qi = 0; qi < QG_; ++qi) {
        osum[qi] = 0.f;
#pragma unroll
        for (int tj = 0; tj < TW_; ++tj) { accL[qi][tj] = 0.f; accI[qi][tj] = 0.f; }
    }

    for (int i = lane; i < SEG4_; i += 64) {
        float4 o[QG_];
#pragma unroll
        for (int qi = 0; qi < QG_; ++qi) {
            o[qi] = o4[(size_t)qi * (HW_ / 4) + i];
            osum[qi] += (o[qi].x + o[qi].y) + (o[qi].z + o[qi].w);
        }
#pragma unroll
        for (int tj = 0; tj < TW_; ++tj) {
            const float4 g = g4[(size_t)(t0 + tj) * (HW_ / 4) + i];
#pragma unroll
            for (int qi = 0; qi < QG_; ++qi) {
                accL[qi][tj] += (fabsf(o[qi].x - g.x) + fabsf(o[qi].y - g.y)) +
                                (fabsf(o[qi].z - g.z) + fabsf(o[qi].w - g.w));
                accI[qi][tj] = fmaf(o[qi].x, g.x, accI[qi][tj]);
                accI[qi][tj] = fmaf(o[qi].y, g.y, accI[qi][tj]);
                accI[qi][tj] = fmaf(o[qi].z, g.z, accI[qi][tj]);
                accI[qi][tj] = fmaf(o[qi].w, g.w, accI[qi][tj]);
            }
        }
    }

    float* rec = ws + ((size_t)grp * S_ + seg) * REC_;
#pragma unroll
    for (int qi = 0; qi < QG_; ++qi) {
#pragma unroll
        for (int tj = 0; tj < TW_; ++tj) {
            const float vL = wave_reduce_sum(accL[qi][tj]);
            const float vI = wave_reduce_sum(accI[qi][tj]);
            if (lane == 0) {
                rec[qi * QREC_ + (t0 + tj)]      = vL;
                rec[qi * QREC_ + 20 + (t0 + tj)] = vI;
            }
        }
        const float vo = wave_reduce_sum(osum[qi]);
        if (wave == 0 && lane == 0) rec[qi * QREC_ + 40] = vo;
    }
}

// Kernel 3: reduce segments + epilogue (softmax class cost + dice).
__global__ __launch_bounds__(64) void finalize_kernel(const float* __restrict__ probs,
                                                      const int*   __restrict__ labels,
                                                      const float* __restrict__ tsum,
                                                      const float* __restrict__ ws,
                                                      float* __restrict__ out) {
    const int bq = blockIdx.x;
    const int b = bq / Q_;
    const int q = bq % Q_;
    const int grp = b * (Q_ / QG_) + q / QG_;
    const int qi  = q % QG_;

    __shared__ float s_logit[C_];
    for (int c = threadIdx.x; c < C_; c += 64)
        s_logit[c] = probs[(size_t)bq * C_ + c];
    __syncthreads();

    const int t = threadIdx.x;
    if (t < T_) {
        float L = 0.f, I = 0.f, os = 0.f;
#pragma unroll
        for (int s = 0; s < S_; ++s) {
            const float* rec = ws + ((size_t)grp * S_ + s) * REC_ + qi * QREC_;
            L += rec[t];
            I += rec[20 + t];
            os += rec[40];
        }
        float m = -INFINITY;
#pragma unroll
        for (int c = 0; c < C_; ++c) m = fmaxf(m, s_logit[c]);
        float sum = 0.f;
#pragma unroll
        for (int c = 0; c < C_; ++c) sum += __expf(s_logit[c] - m);
        const int lab = labels[b * T_ + t];
        const float p = __expf(s_logit[lab] - m) / sum;

        const float denom = os + tsum[b * T_ + t];
        const float dice = 1.f - (2.f * I + 1.f) / (denom + 1.f);

        out[(size_t)bq * T_ + t] = L - p + dice;
    }
}

extern "C" void kernel_launch(void* const* d_in, const int* in_sizes, int n_in,
                              void* d_out, int out_size, void* d_ws, size_t ws_size,
                              hipStream_t stream) {
    const float* out_probs     = (const float*)d_in[0]; // [B,Q,C]
    const float* out_masks     = (const float*)d_in[1]; // [B,Q,H,W]
    const float* target_masks  = (const float*)d_in[2]; // [B,T,H,W]
    const int*   target_labels = (const int*)d_in[3];   // [B,T]
    float* out = (float*)d_out;                         // [B,Q,T]

    float* tsum     = (float*)d_ws;                     // B*T floats
    float* partials = tsum + B_ * T_;                   // GROUPS_*S_*REC_ floats (~525 KB)

    tgt_sum_kernel<<<B_ * T_, 256, 0, stream>>>(target_masks, tsum);
    partial_kernel<<<GROUPS_ * S_, 256, 0, stream>>>(out_masks, target_masks, partials);
    finalize_kernel<<<B_ * Q_, 64, 0, stream>>>(out_probs, target_labels, tsum, partials, out);
}

// Round 5
// 38.801 us; speedup vs baseline: 2.2109x; 1.1262x over previous
//
#include <hip/hip_runtime.h>
#include <hip/hip_bf16.h>
#include <math.h>

// Problem constants: B=4, Q=100, T=20, H=W=128 (HW=16384), C=80
#define B_ 4
#define Q_ 100
#define T_ 20
#define C_ 80
#define HW_ 16384

#define S_ 16                    // segments over HW
#define QG_ 4                    // queries per group/block
#define GPB_ (Q_ / QG_)          // 25 groups per batch
#define GROUPS_ (B_ * GPB_)      // 100
#define SEG4_ (HW_ / S_ / 4)     // 256 float4 per segment
#define TW_ 5                    // t's per wave (4 waves * 5 = T)
#define SUBS_ 4                  // partial-reduce width (lanes 0..3)
#define QREC_ 41                 // per-q: 20 L + 20 I + 1 osum
#define RECA_ (QG_ * QREC_ * SUBS_)  // 656 floats
#define REC_ (RECA_ + T_ * SUBS_)    // 736 floats per (group,seg) record

// 4-stage reduce: lanes 0..3 end with disjoint 16-lane partial sums.
__device__ __forceinline__ float wave_reduce4(float v) {
    v += __shfl_down(v, 32);
    v += __shfl_down(v, 16);
    v += __shfl_down(v, 8);
    v += __shfl_down(v, 4);
    return v;
}

// Kernel 1: partial sums per (4-query group, segment).
// 256 threads = 4 waves; wave w handles t in [5w,5w+5) for all 4 queries,
// and also accumulates the per-t target pixel sums (gsum) for the dice denom.
__global__ __launch_bounds__(256) void partial_kernel(const float* __restrict__ outm,
                                                      const float* __restrict__ tgtm,
                                                      float* __restrict__ ws) {
    const int seg = blockIdx.x & (S_ - 1);
    const int grp = blockIdx.x / S_;
    const int b     = grp / GPB_;
    const int qbase = (grp % GPB_) * QG_;

    const int lane = threadIdx.x & 63;
    const int wave = threadIdx.x >> 6;
    const int t0   = wave * TW_;

    const float4* o4 = (const float4*)(outm + ((size_t)b * Q_ + qbase) * HW_) + seg * SEG4_;
    const float4* g4 = (const float4*)(tgtm + (size_t)b * T_ * HW_) + seg * SEG4_;

    float accL[QG_][TW_];
    float accI[QG_][TW_];
    float osum[QG_];
    float gsum[TW_];
#pragma unroll
    for (int qi = 0; qi < QG_; ++qi) {
        osum[qi] = 0.f;
#pragma unroll
        for (int tj = 0; tj < TW_; ++tj) { accL[qi][tj] = 0.f; accI[qi][tj] = 0.f; }
    }
#pragma unroll
    for (int tj = 0; tj < TW_; ++tj) gsum[tj] = 0.f;

    for (int i = lane; i < SEG4_; i += 64) {
        float4 o[QG_];
#pragma unroll
        for (int qi = 0; qi < QG_; ++qi) {
            o[qi] = o4[(size_t)qi * (HW_ / 4) + i];
            osum[qi] += (o[qi].x + o[qi].y) + (o[qi].z + o[qi].w);
        }
#pragma unroll
        for (int tj = 0; tj < TW_; ++tj) {
            const float4 g = g4[(size_t)(t0 + tj) * (HW_ / 4) + i];
            gsum[tj] += (g.x + g.y) + (g.z + g.w);
#pragma unroll
            for (int qi = 0; qi < QG_; ++qi) {
                accL[qi][tj] += (fabsf(o[qi].x - g.x) + fabsf(o[qi].y - g.y)) +
                                (fabsf(o[qi].z - g.z) + fabsf(o[qi].w - g.w));
                accI[qi][tj] = fmaf(o[qi].x, g.x, accI[qi][tj]);
                accI[qi][tj] = fmaf(o[qi].y, g.y, accI[qi][tj]);
                accI[qi][tj] = fmaf(o[qi].z, g.z, accI[qi][tj]);
                accI[qi][tj] = fmaf(o[qi].w, g.w, accI[qi][tj]);
            }
        }
    }

    float* rec = ws + ((size_t)grp * S_ + seg) * REC_;
#pragma unroll
    for (int qi = 0; qi < QG_; ++qi) {
#pragma unroll
        for (int tj = 0; tj < TW_; ++tj) {
            const float vL = wave_reduce4(accL[qi][tj]);
            const float vI = wave_reduce4(accI[qi][tj]);
            if (lane < SUBS_) {
                rec[(qi * QREC_ + (t0 + tj)) * SUBS_ + lane]      = vL;
                rec[(qi * QREC_ + 20 + (t0 + tj)) * SUBS_ + lane] = vI;
            }
        }
        const float vo = wave_reduce4(osum[qi]);
        if (wave == 0 && lane < SUBS_) rec[(qi * QREC_ + 40) * SUBS_ + lane] = vo;
    }
#pragma unroll
    for (int tj = 0; tj < TW_; ++tj) {
        const float vg = wave_reduce4(gsum[tj]);
        if (lane < SUBS_) rec[RECA_ + (t0 + tj) * SUBS_ + lane] = vg;
    }
}

// Kernel 2: reduce segments/sub-partials + epilogue (softmax class cost + dice).
__global__ __launch_bounds__(64) void finalize_kernel(const float* __restrict__ probs,
                                                      const int*   __restrict__ labels,
                                                      const float* __restrict__ ws,
                                                      float* __restrict__ out) {
    const int bq = blockIdx.x;
    const int b = bq / Q_;
    const int q = bq % Q_;
    const int grp  = b * GPB_ + q / QG_;
    const int grp0 = b * GPB_;
    const int qi   = q % QG_;

    __shared__ float s_logit[C_];
    for (int c = threadIdx.x; c < C_; c += 64)
        s_logit[c] = probs[(size_t)bq * C_ + c];
    __syncthreads();

    const int t = threadIdx.x;
    if (t < T_) {
        float L = 0.f, I = 0.f, os = 0.f, ts = 0.f;
#pragma unroll
        for (int s = 0; s < S_; ++s) {
            const float4* r4  = (const float4*)(ws + ((size_t)grp * S_ + s) * REC_);
            const float4* r40 = (const float4*)(ws + ((size_t)grp0 * S_ + s) * REC_);
            const float4 a = r4[qi * QREC_ + t];
            const float4 v = r4[qi * QREC_ + 20 + t];
            const float4 c = r4[qi * QREC_ + 40];
            const float4 d = r40[RECA_ / 4 + t];
            L  += (a.x + a.y) + (a.z + a.w);
            I  += (v.x + v.y) + (v.z + v.w);
            os += (c.x + c.y) + (c.z + c.w);
            ts += (d.x + d.y) + (d.z + d.w);
        }
        float m = -INFINITY;
#pragma unroll
        for (int c = 0; c < C_; ++c) m = fmaxf(m, s_logit[c]);
        float sum = 0.f;
#pragma unroll
        for (int c = 0; c < C_; ++c) sum += __expf(s_logit[c] - m);
        const int lab = labels[b * T_ + t];
        const float p = __expf(s_logit[lab] - m) / sum;

        const float denom = os + ts;
        const float dice = 1.f - (2.f * I + 1.f) / (denom + 1.f);

        out[(size_t)bq * T_ + t] = L - p + dice;
    }
}

extern "C" void kernel_launch(void* const* d_in, const int* in_sizes, int n_in,
                              void* d_out, int out_size, void* d_ws, size_t ws_size,
                              hipStream_t stream) {
    const float* out_probs     = (const float*)d_in[0]; // [B,Q,C]
    const float* out_masks     = (const float*)d_in[1]; // [B,Q,H,W]
    const float* target_masks  = (const float*)d_in[2]; // [B,T,H,W]
    const int*   target_labels = (const int*)d_in[3];   // [B,T]
    float* out = (float*)d_out;                         // [B,Q,T]

    float* partials = (float*)d_ws;                     // GROUPS_*S_*REC_ floats (~4.5 MB)

    partial_kernel<<<GROUPS_ * S_, 256, 0, stream>>>(out_masks, target_masks, partials);
    finalize_kernel<<<B_ * Q_, 64, 0, stream>>>(out_probs, target_labels, partials, out);
}